// Round 10
// baseline (62.802 us; speedup 1.0000x reference)
//
#include <hip/hip_runtime.h>
#include <hip/hip_bf16.h>
#include <math.h>

#define N_   4096
#define DIN  512
#define D_   64

typedef __attribute__((ext_vector_type(8))) short  bf16x8;
typedef __attribute__((ext_vector_type(4))) float  f32x4;

#define ZERO4 ((f32x4){0.f, 0.f, 0.f, 0.f})

__device__ __forceinline__ unsigned short bf16rne(float x) {
    unsigned u = __float_as_uint(x);
    return (unsigned short)((u + 0x7FFFu + ((u >> 16) & 1u)) >> 16);
}
__device__ __forceinline__ unsigned cvt2(float a, float b) {
    __hip_bfloat162 h = __float22bfloat162_rn(make_float2(a, b));
    unsigned u; __builtin_memcpy(&u, &h, 4);
    return u;
}
__device__ __forceinline__ uint2 cvt4(float4 v) {
    return make_uint2(cvt2(v.x, v.y), cvt2(v.z, v.w));
}
// XOR-swizzled short-index for [row][128B] tiles: byte_in_row ^ ((row&7)<<4)
__device__ __forceinline__ int swz(int row, int byte_in_row) {
    return (row * 128 + (byte_in_row ^ ((row & 7) << 4))) >> 1;
}

// async 16B global->LDS (linear LDS dest = wave base + lane*16)
#define GLD16(gp, lp)                                                          \
    __builtin_amdgcn_global_load_lds(                                          \
        (const __attribute__((address_space(1))) unsigned int*)(gp),           \
        (__attribute__((address_space(3))) unsigned int*)(lp), 16, 0, 0)

// slot prefix for 128-row q-tiles (slices(qi) = (qi>>3)+1; 80 per batch)
__device__ __forceinline__ int pb128(int qi) {
    const int g = qi >> 3, r = qi & 7;
    return 4 * g * (g + 1) + r * (g + 1);
}
#define PART128_F 8320   // 64*128 O^T + 128 l (floats)

// ---------------------------------------------------------------------------
// Projection GEMM (unchanged): X fp32 -> {K,Q n-major bf16, Vt o-major bf16}.
// 512 thr / 8 waves, BM=64, BK=64, double-buffered, swizzled tiles.
// ---------------------------------------------------------------------------
__global__ __launch_bounds__(512) void proj_kernel(
    const float* __restrict__ X, const float* __restrict__ Wk,
    const float* __restrict__ Wq, const float* __restrict__ Wv,
    unsigned short* __restrict__ Kb, unsigned short* __restrict__ Qb,
    unsigned short* __restrict__ Vt)
{
    __shared__ unsigned short Xs[2][64 * 64];
    __shared__ unsigned short Ws[2][192 * 64];

    const int tid  = threadIdx.x;
    const int lane = tid & 63;
    const int w    = tid >> 6;
    const int q15  = lane & 15;
    const int hi   = lane >> 4;
    const int rt   = w >> 1;
    const int oh   = w & 1;
    const int rbase = blockIdx.x * 64;

    float4 xr[2], wr[6];

    auto loadT = [&](int kc) {
        #pragma unroll
        for (int i = 0; i < 2; ++i) {
            const int idx = tid + i * 512;
            xr[i] = *(const float4*)(X + (size_t)(rbase + (idx >> 4)) * DIN + kc + (idx & 15) * 4);
        }
        #pragma unroll
        for (int i = 0; i < 6; ++i) {
            const int idx  = tid + i * 512;
            const int wrow = idx >> 4;
            const float* Wp = (wrow < 64)  ? Wk + (size_t)wrow * DIN
                            : (wrow < 128) ? Wq + (size_t)(wrow - 64) * DIN
                                           : Wv + (size_t)(wrow - 128) * DIN;
            wr[i] = *(const float4*)(Wp + kc + (idx & 15) * 4);
        }
    };
    auto storeT = [&](int p) {
        #pragma unroll
        for (int i = 0; i < 2; ++i) {
            const int idx = tid + i * 512;
            *(uint2*)&Xs[p][swz(idx >> 4, (idx & 15) * 8)] = cvt4(xr[i]);
        }
        #pragma unroll
        for (int i = 0; i < 6; ++i) {
            const int idx = tid + i * 512;
            *(uint2*)&Ws[p][swz(idx >> 4, (idx & 15) * 8)] = cvt4(wr[i]);
        }
    };

    f32x4 acc[6];
    #pragma unroll
    for (int i = 0; i < 6; ++i) acc[i] = ZERO4;

    loadT(0);
    int p = 0;
    for (int it = 0; it < 8; ++it) {
        storeT(p);
        __syncthreads();
        if (it < 7) loadT((it + 1) * 64);
        #pragma unroll
        for (int ks = 0; ks < 2; ++ks) {
            bf16x8 af = *(const bf16x8*)&Xs[p][swz(rt * 16 + q15, ks * 64 + hi * 16)];
            #pragma unroll
            for (int j = 0; j < 6; ++j) {
                bf16x8 bfr = *(const bf16x8*)&Ws[p][swz((oh * 6 + j) * 16 + q15, ks * 64 + hi * 16)];
                acc[j] = __builtin_amdgcn_mfma_f32_16x16x32_bf16(af, bfr, acc[j], 0, 0, 0);
            }
        }
        p ^= 1;
    }

    unsigned short* Os = &Ws[0][0];               // [64n][66o] V staging scratch
    #pragma unroll
    for (int j = 0; j < 6; ++j) {
        const int og = oh * 6 + j;
        #pragma unroll
        for (int r = 0; r < 4; ++r) {
            const int n = rt * 16 + hi * 4 + r;
            const int o = og * 16 + q15;
            unsigned short v = bf16rne(acc[j][r]);
            if (og < 4)      Kb[(size_t)(rbase + n) * D_ + o]        = v;
            else if (og < 8) Qb[(size_t)(rbase + n) * D_ + (o - 64)] = v;
            else             Os[n * 66 + (o - 128)]                  = v;
        }
    }
    __syncthreads();
    {
        const int o  = tid >> 3;
        const int ng = (tid & 7) * 8;
        unsigned short tmp[8];
        #pragma unroll
        for (int i = 0; i < 8; ++i) tmp[i] = Os[(ng + i) * 66 + o];
        const int b  = rbase >> 12;
        const int nb = rbase & (N_ - 1);
        *(uint4*)(Vt + ((size_t)b * D_ + o) * N_ + nb + ng) = *(uint4*)&tmp[0];
    }
}

// ---------------------------------------------------------------------------
// Pass 1: partial attention. Block = 4 waves x 128 q-rows (wave w owns rows
// w*32..+32 as 2 Q-streams sharing K/V LDS reads), k-slice of <=16 chunks.
// K/V staged via global_load_lds (linear dest, inverse-swizzled source),
// double-buffered, ONE barrier/chunk. Causal mask applied on the LAST TWO
// chunks (128-row tile spans 2 diagonal chunks — R9 bug was masking only 1).
// No-max softmax -> additive partials [64d][128q]+l[128] per slice.
// ---------------------------------------------------------------------------
__global__ __launch_bounds__(256) void attn_part_kernel(
    const unsigned short* __restrict__ Qb, const unsigned short* __restrict__ Kb,
    const unsigned short* __restrict__ Vt, float* __restrict__ Pws)
{
    __shared__ unsigned short Ks[2][64 * 64];     // [key][d] swizzled
    __shared__ unsigned short Vs[2][64 * 64];     // [d][key] swizzled
    __shared__ unsigned short Pb[4][32 * 64];     // per-wave P [q][key] swizzled

    const int tid  = threadIdx.x;
    const int lane = tid & 63;
    const int w    = tid >> 6;
    const int q15  = lane & 15;
    const int hi   = lane >> 4;

    const int b = blockIdx.x & 3;                 // XCD-pinned batch
    const int u = blockIdx.x >> 2;                // 0..79, big blocks first
    int sl, qi;
    if      (u < 32) { sl = 0; qi = 31 - u; }
    else if (u < 56) { sl = 1; qi = 31 - (u - 32); }
    else if (u < 72) { sl = 2; qi = 31 - (u - 56); }
    else             { sl = 3; qi = 31 - (u - 72); }
    const int nch  = 2 * qi + 2;
    const int cbeg = sl * 16;
    const int cend = min(nch, cbeg + 16);
    const int qb   = qi * 128;

    const unsigned short* Qp = Qb + (size_t)b * N_ * D_;
    const unsigned short* Kp = Kb + (size_t)b * N_ * D_;
    const unsigned short* Vp = Vt + (size_t)b * D_ * N_;

    bf16x8 qf[2][2];
    #pragma unroll
    for (int qq = 0; qq < 2; ++qq)
        #pragma unroll
        for (int ks = 0; ks < 2; ++ks)
            qf[qq][ks] = *(const bf16x8*)(Qp + (size_t)(qb + w * 32 + qq * 16 + q15) * D_ + ks * 32 + hi * 8);

    f32x4 accO[2][4];
    #pragma unroll
    for (int qq = 0; qq < 2; ++qq)
        #pragma unroll
        for (int dt = 0; dt < 4; ++dt) accO[qq][dt] = ZERO4;
    float lsum[2] = {0.f, 0.f};

    // inverse-swizzled per-lane source offset (shorts): 16B slot (l&7)^(l>>3)
    const int lsw = 8 * ((lane & 7) ^ (lane >> 3));

    auto issueChunk = [&](int p, int c) {
        const int kb2 = c * 64;
        #pragma unroll
        for (int i = 0; i < 2; ++i) {
            const int r8  = w * 2 + i;            // 8-row group 0..7
            const int row = r8 * 8 + (lane >> 3);
            GLD16(Kp + (size_t)(kb2 + row) * D_ + lsw, &Ks[p][r8 * 512]);
            GLD16(Vp + (size_t)row * N_ + kb2 + lsw,   &Vs[p][r8 * 512]);
        }
    };

    issueChunk(0, cbeg);
    __syncthreads();                              // drains vmcnt + barrier

    unsigned short* Pw = &Pb[w][0];
    const float SC = 0.125f * 1.44269504f;        // log2-domain scale
    int p = 0;

    for (int c = cbeg; c < cend; ++c) {
        if (c + 1 < cend) issueChunk(p ^ 1, c + 1);   // overlap with compute
        const int kbase = c * 64;
        const bool edge = (c >= nch - 2);         // both diagonal chunks

        // QK^T (swapped): K frags shared by both Q-streams
        f32x4 sv[2][4];
        #pragma unroll
        for (int kt = 0; kt < 4; ++kt) {
            bf16x8 k0 = *(const bf16x8*)&Ks[p][swz(kt * 16 + q15, hi * 16)];
            bf16x8 k1 = *(const bf16x8*)&Ks[p][swz(kt * 16 + q15, 64 + hi * 16)];
            sv[0][kt] = __builtin_amdgcn_mfma_f32_16x16x32_bf16(k0, qf[0][0], ZERO4, 0, 0, 0);
            sv[0][kt] = __builtin_amdgcn_mfma_f32_16x16x32_bf16(k1, qf[0][1], sv[0][kt], 0, 0, 0);
            sv[1][kt] = __builtin_amdgcn_mfma_f32_16x16x32_bf16(k0, qf[1][0], ZERO4, 0, 0, 0);
            sv[1][kt] = __builtin_amdgcn_mfma_f32_16x16x32_bf16(k1, qf[1][1], sv[1][kt], 0, 0, 0);
        }

        // softmax-lite: scale, causal mask (diagonal chunks), exp2, l, pack
        #pragma unroll
        for (int qq = 0; qq < 2; ++qq) {
            const int qg = qb + w * 32 + qq * 16 + q15;
            #pragma unroll
            for (int kt = 0; kt < 4; ++kt) {
                float pv[4];
                #pragma unroll
                for (int r = 0; r < 4; ++r) {
                    float v = sv[qq][kt][r] * SC;
                    const int kg = kbase + kt * 16 + hi * 4 + r;
                    if (edge) v = (kg <= qg) ? v : -INFINITY;
                    pv[r] = __builtin_amdgcn_exp2f(v);
                    lsum[qq] += pv[r];
                }
                *(uint2*)&Pw[swz(qq * 16 + q15, kt * 32 + hi * 8)] =
                    make_uint2(cvt2(pv[0], pv[1]), cvt2(pv[2], pv[3]));
            }
        }

        // PV: O^T += V^T * P^T  (V frags shared by both Q-streams)
        #pragma unroll
        for (int ks2 = 0; ks2 < 2; ++ks2) {
            bf16x8 vf[4];
            #pragma unroll
            for (int dt = 0; dt < 4; ++dt)
                vf[dt] = *(const bf16x8*)&Vs[p][swz(dt * 16 + q15, ks2 * 64 + hi * 16)];
            #pragma unroll
            for (int qq = 0; qq < 2; ++qq) {
                bf16x8 pf = *(const bf16x8*)&Pw[swz(qq * 16 + q15, ks2 * 64 + hi * 16)];
                #pragma unroll
                for (int dt = 0; dt < 4; ++dt)
                    accO[qq][dt] = __builtin_amdgcn_mfma_f32_16x16x32_bf16(vf[dt], pf, accO[qq][dt], 0, 0, 0);
            }
        }

        __syncthreads();                          // next buffer staged + bufs free
        p ^= 1;
    }

    // l reduce over hi groups
    #pragma unroll
    for (int qq = 0; qq < 2; ++qq) {
        lsum[qq] += __shfl_xor(lsum[qq], 16);
        lsum[qq] += __shfl_xor(lsum[qq], 32);
    }

    // partial write: O^T [64d][128q], wave w owns q-cols w*32..+32
    float* partO = Pws + ((size_t)b * 80 + pb128(qi) + sl) * PART128_F;
    #pragma unroll
    for (int qq = 0; qq < 2; ++qq) {
        #pragma unroll
        for (int dt = 0; dt < 4; ++dt)
            #pragma unroll
            for (int r = 0; r < 4; ++r)
                partO[(dt * 16 + hi * 4 + r) * 128 + w * 32 + qq * 16 + q15] = accO[qq][dt][r];
        if (hi == 0) partO[8192 + w * 32 + qq * 16 + q15] = lsum[qq];
    }
}

// ---------------------------------------------------------------------------
// Pass 2: sum <=4 slice partials per (b, 128-row q-tile), transpose via LDS,
// normalize by l, write O.
// ---------------------------------------------------------------------------
__global__ __launch_bounds__(256) void attn_merge_kernel(
    const float* __restrict__ Pws, float* __restrict__ O)
{
    __shared__ float Tr[64 * 132];                // [d][q] pad 132
    __shared__ float Ls[128];

    const int tid = threadIdx.x;
    const int b   = blockIdx.x & 3;
    const int qi  = blockIdx.x >> 2;
    const int np  = (qi >> 3) + 1;
    const float* base = Pws + ((size_t)b * 80 + pb128(qi)) * PART128_F;

    {
        const int d  = tid >> 2;
        const int qg = (tid & 3) * 32;
        float s[32];
        #pragma unroll
        for (int i = 0; i < 32; ++i) s[i] = 0.f;
        for (int pp = 0; pp < np; ++pp) {
            const float* sp = base + (size_t)pp * PART128_F + d * 128 + qg;
            #pragma unroll
            for (int i = 0; i < 8; ++i) {
                float4 v = *(const float4*)(sp + i * 4);
                s[4*i]   += v.x; s[4*i+1] += v.y;
                s[4*i+2] += v.z; s[4*i+3] += v.w;
            }
        }
        #pragma unroll
        for (int i = 0; i < 32; ++i) Tr[d * 132 + qg + i] = s[i];
    }
    if (tid < 128) {
        float L = 0.f;
        for (int pp = 0; pp < np; ++pp) L += base[(size_t)pp * PART128_F + 8192 + tid];
        Ls[tid] = 1.0f / L;
    }
    __syncthreads();
    {
        const int q  = tid >> 1;
        const int dg = (tid & 1) * 32;
        const float rL = Ls[q];
        float* dst = O + ((size_t)b * N_ + qi * 128 + q) * D_ + dg;
        #pragma unroll
        for (int i = 0; i < 8; ++i) {
            float4 v = make_float4(Tr[(dg + 4*i    ) * 132 + q] * rL,
                                   Tr[(dg + 4*i + 1) * 132 + q] * rL,
                                   Tr[(dg + 4*i + 2) * 132 + q] * rL,
                                   Tr[(dg + 4*i + 3) * 132 + q] * rL);
            *(float4*)(dst + i * 4) = v;
        }
    }
}

// ---------------------------------------------------------------------------
extern "C" void kernel_launch(void* const* d_in, const int* in_sizes, int n_in,
                              void* d_out, int out_size, void* d_ws, size_t ws_size,
                              hipStream_t stream)
{
    const float* x  = (const float*)d_in[0];
    const float* Wk = (const float*)d_in[1];
    const float* Wq = (const float*)d_in[2];
    const float* Wv = (const float*)d_in[3];
    float* O = (float*)d_out;

    const size_t per = (size_t)4 * N_ * D_;       // 1M bf16 elements each
    unsigned short* Kb = (unsigned short*)d_ws;
    unsigned short* Qb = Kb + per;
    unsigned short* Vt = Qb + per;
    float* Pws = (float*)((char*)d_ws + 3 * per * sizeof(unsigned short));

    proj_kernel<<<dim3(4 * N_ / 64), 512, 0, stream>>>(x, Wk, Wq, Wv, Kb, Qb, Vt);
    attn_part_kernel<<<dim3(320), 256, 0, stream>>>(Qb, Kb, Vt, Pws);
    attn_merge_kernel<<<dim3(128), 256, 0, stream>>>(Pws, O);
}

// Round 11
// 56.933 us; speedup vs baseline: 1.1031x; 1.1031x over previous
//
#include <hip/hip_runtime.h>
#include <hip/hip_bf16.h>
#include <math.h>

#define N_   4096
#define DIN  512
#define D_   64

typedef __attribute__((ext_vector_type(8))) short  bf16x8;
typedef __attribute__((ext_vector_type(4))) float  f32x4;

#define ZERO4 ((f32x4){0.f, 0.f, 0.f, 0.f})

__device__ __forceinline__ unsigned short bf16rne(float x) {
    unsigned u = __float_as_uint(x);
    return (unsigned short)((u + 0x7FFFu + ((u >> 16) & 1u)) >> 16);
}
__device__ __forceinline__ unsigned cvt2(float a, float b) {
    __hip_bfloat162 h = __float22bfloat162_rn(make_float2(a, b));
    unsigned u; __builtin_memcpy(&u, &h, 4);
    return u;
}
__device__ __forceinline__ uint2 cvt4(float4 v) {
    return make_uint2(cvt2(v.x, v.y), cvt2(v.z, v.w));
}
// XOR-swizzled short-index for [row][128B] tiles: byte_in_row ^ ((row&7)<<4)
__device__ __forceinline__ int swz(int row, int byte_in_row) {
    return (row * 128 + (byte_in_row ^ ((row & 7) << 4))) >> 1;
}

// async 16B global->LDS (linear LDS dest = wave base + lane*16)
#define GLD16(gp, lp)                                                          \
    __builtin_amdgcn_global_load_lds(                                          \
        (const __attribute__((address_space(1))) unsigned int*)(gp),           \
        (__attribute__((address_space(3))) unsigned int*)(lp), 16, 0, 0)

// slices per 128-row q-tile: s(qi) = (qi>>2)+1 (8-chunk slices, nch = 2qi+2)
// prefix: pb128(qi) = sum_{j<qi} s(j) = qi + 2g(g-1) + r*g, g=qi>>2, r=qi&3
// total 144 slots per batch
__device__ __forceinline__ int pb128(int qi) {
    const int g = qi >> 2, r = qi & 3;
    return qi + 2 * g * (g - 1) + r * g;
}
#define PART128_F 8320   // 64*128 O^T + 128 l (floats)

// ---------------------------------------------------------------------------
// Projection GEMM (unchanged): X fp32 -> {K,Q n-major bf16, Vt o-major bf16}.
// 512 thr / 8 waves, BM=64, BK=64, double-buffered, swizzled tiles.
// ---------------------------------------------------------------------------
__global__ __launch_bounds__(512) void proj_kernel(
    const float* __restrict__ X, const float* __restrict__ Wk,
    const float* __restrict__ Wq, const float* __restrict__ Wv,
    unsigned short* __restrict__ Kb, unsigned short* __restrict__ Qb,
    unsigned short* __restrict__ Vt)
{
    __shared__ unsigned short Xs[2][64 * 64];
    __shared__ unsigned short Ws[2][192 * 64];

    const int tid  = threadIdx.x;
    const int lane = tid & 63;
    const int w    = tid >> 6;
    const int q15  = lane & 15;
    const int hi   = lane >> 4;
    const int rt   = w >> 1;
    const int oh   = w & 1;
    const int rbase = blockIdx.x * 64;

    float4 xr[2], wr[6];

    auto loadT = [&](int kc) {
        #pragma unroll
        for (int i = 0; i < 2; ++i) {
            const int idx = tid + i * 512;
            xr[i] = *(const float4*)(X + (size_t)(rbase + (idx >> 4)) * DIN + kc + (idx & 15) * 4);
        }
        #pragma unroll
        for (int i = 0; i < 6; ++i) {
            const int idx  = tid + i * 512;
            const int wrow = idx >> 4;
            const float* Wp = (wrow < 64)  ? Wk + (size_t)wrow * DIN
                            : (wrow < 128) ? Wq + (size_t)(wrow - 64) * DIN
                                           : Wv + (size_t)(wrow - 128) * DIN;
            wr[i] = *(const float4*)(Wp + kc + (idx & 15) * 4);
        }
    };
    auto storeT = [&](int p) {
        #pragma unroll
        for (int i = 0; i < 2; ++i) {
            const int idx = tid + i * 512;
            *(uint2*)&Xs[p][swz(idx >> 4, (idx & 15) * 8)] = cvt4(xr[i]);
        }
        #pragma unroll
        for (int i = 0; i < 6; ++i) {
            const int idx = tid + i * 512;
            *(uint2*)&Ws[p][swz(idx >> 4, (idx & 15) * 8)] = cvt4(wr[i]);
        }
    };

    f32x4 acc[6];
    #pragma unroll
    for (int i = 0; i < 6; ++i) acc[i] = ZERO4;

    loadT(0);
    int p = 0;
    for (int it = 0; it < 8; ++it) {
        storeT(p);
        __syncthreads();
        if (it < 7) loadT((it + 1) * 64);
        #pragma unroll
        for (int ks = 0; ks < 2; ++ks) {
            bf16x8 af = *(const bf16x8*)&Xs[p][swz(rt * 16 + q15, ks * 64 + hi * 16)];
            #pragma unroll
            for (int j = 0; j < 6; ++j) {
                bf16x8 bfr = *(const bf16x8*)&Ws[p][swz((oh * 6 + j) * 16 + q15, ks * 64 + hi * 16)];
                acc[j] = __builtin_amdgcn_mfma_f32_16x16x32_bf16(af, bfr, acc[j], 0, 0, 0);
            }
        }
        p ^= 1;
    }

    unsigned short* Os = &Ws[0][0];               // [64n][66o] V staging scratch
    #pragma unroll
    for (int j = 0; j < 6; ++j) {
        const int og = oh * 6 + j;
        #pragma unroll
        for (int r = 0; r < 4; ++r) {
            const int n = rt * 16 + hi * 4 + r;
            const int o = og * 16 + q15;
            unsigned short v = bf16rne(acc[j][r]);
            if (og < 4)      Kb[(size_t)(rbase + n) * D_ + o]        = v;
            else if (og < 8) Qb[(size_t)(rbase + n) * D_ + (o - 64)] = v;
            else             Os[n * 66 + (o - 128)]                  = v;
        }
    }
    __syncthreads();
    {
        const int o  = tid >> 3;
        const int ng = (tid & 7) * 8;
        unsigned short tmp[8];
        #pragma unroll
        for (int i = 0; i < 8; ++i) tmp[i] = Os[(ng + i) * 66 + o];
        const int b  = rbase >> 12;
        const int nb = rbase & (N_ - 1);
        *(uint4*)(Vt + ((size_t)b * D_ + o) * N_ + nb + ng) = *(uint4*)&tmp[0];
    }
}

// ---------------------------------------------------------------------------
// Pass 1: partial attention. Block = 4 waves x 128 q-rows (wave w owns rows
// w*32..+32 as 2 Q-streams sharing K/V LDS reads), k-slice of <=8 chunks ->
// 576 blocks (~2.25/CU resident, 48KB LDS -> 3/CU cap). K/V staged via
// global_load_lds (linear dest, inverse-swizzled source), double-buffered,
// ONE barrier/chunk. Causal mask on last TWO chunks (nch even -> both always
// in the last slice). No-max softmax -> additive partials.
// ---------------------------------------------------------------------------
__global__ __launch_bounds__(256) void attn_part_kernel(
    const unsigned short* __restrict__ Qb, const unsigned short* __restrict__ Kb,
    const unsigned short* __restrict__ Vt, float* __restrict__ Pws)
{
    __shared__ unsigned short Ks[2][64 * 64];     // [key][d] swizzled
    __shared__ unsigned short Vs[2][64 * 64];     // [d][key] swizzled
    __shared__ unsigned short Pb[4][32 * 64];     // per-wave P [q][key] swizzled

    const int tid  = threadIdx.x;
    const int lane = tid & 63;
    const int w    = tid >> 6;
    const int q15  = lane & 15;
    const int hi   = lane >> 4;

    const int b = blockIdx.x & 3;                 // XCD-pinned batch
    const int u = blockIdx.x >> 2;                // 0..143
    const int v = 143 - u;                        // big q-tiles first
    int g = 0;
    #pragma unroll
    for (int t = 0; t < 7; ++t)
        if (2 * (t + 1) * (t + 2) <= v) g = t + 1;
    const int idx = v - 2 * g * (g + 1);
    const int qs  = idx / (g + 1);
    const int qi  = 4 * g + qs;                   // 0..31
    const int sl  = idx - qs * (g + 1);           // 0..g

    const int nch  = 2 * qi + 2;
    const int cbeg = sl * 8;
    const int cend = min(nch, cbeg + 8);
    const int qb   = qi * 128;

    const unsigned short* Qp = Qb + (size_t)b * N_ * D_;
    const unsigned short* Kp = Kb + (size_t)b * N_ * D_;
    const unsigned short* Vp = Vt + (size_t)b * D_ * N_;

    bf16x8 qf[2][2];
    #pragma unroll
    for (int qq = 0; qq < 2; ++qq)
        #pragma unroll
        for (int ks = 0; ks < 2; ++ks)
            qf[qq][ks] = *(const bf16x8*)(Qp + (size_t)(qb + w * 32 + qq * 16 + q15) * D_ + ks * 32 + hi * 8);

    f32x4 accO[2][4];
    #pragma unroll
    for (int qq = 0; qq < 2; ++qq)
        #pragma unroll
        for (int dt = 0; dt < 4; ++dt) accO[qq][dt] = ZERO4;
    float lsum[2] = {0.f, 0.f};

    // inverse-swizzled per-lane source offset (shorts): 16B slot (l&7)^(l>>3)
    const int lsw = 8 * ((lane & 7) ^ (lane >> 3));

    auto issueChunk = [&](int p, int c) {
        const int kb2 = c * 64;
        #pragma unroll
        for (int i = 0; i < 2; ++i) {
            const int r8  = w * 2 + i;            // 8-row group 0..7
            const int row = r8 * 8 + (lane >> 3);
            GLD16(Kp + (size_t)(kb2 + row) * D_ + lsw, &Ks[p][r8 * 512]);
            GLD16(Vp + (size_t)row * N_ + kb2 + lsw,   &Vs[p][r8 * 512]);
        }
    };

    issueChunk(0, cbeg);
    __syncthreads();                              // drains vmcnt + barrier

    unsigned short* Pw = &Pb[w][0];
    const float SC = 0.125f * 1.44269504f;        // log2-domain scale
    int p = 0;

    for (int c = cbeg; c < cend; ++c) {
        if (c + 1 < cend) issueChunk(p ^ 1, c + 1);   // overlap with compute
        const int kbase = c * 64;
        const bool edge = (c >= nch - 2);         // both diagonal chunks

        // QK^T (swapped): K frags shared by both Q-streams
        f32x4 sv[2][4];
        #pragma unroll
        for (int kt = 0; kt < 4; ++kt) {
            bf16x8 k0 = *(const bf16x8*)&Ks[p][swz(kt * 16 + q15, hi * 16)];
            bf16x8 k1 = *(const bf16x8*)&Ks[p][swz(kt * 16 + q15, 64 + hi * 16)];
            sv[0][kt] = __builtin_amdgcn_mfma_f32_16x16x32_bf16(k0, qf[0][0], ZERO4, 0, 0, 0);
            sv[0][kt] = __builtin_amdgcn_mfma_f32_16x16x32_bf16(k1, qf[0][1], sv[0][kt], 0, 0, 0);
            sv[1][kt] = __builtin_amdgcn_mfma_f32_16x16x32_bf16(k0, qf[1][0], ZERO4, 0, 0, 0);
            sv[1][kt] = __builtin_amdgcn_mfma_f32_16x16x32_bf16(k1, qf[1][1], sv[1][kt], 0, 0, 0);
        }

        // softmax-lite: scale, causal mask (diagonal chunks), exp2, l, pack
        #pragma unroll
        for (int qq = 0; qq < 2; ++qq) {
            const int qg = qb + w * 32 + qq * 16 + q15;
            #pragma unroll
            for (int kt = 0; kt < 4; ++kt) {
                float pv[4];
                #pragma unroll
                for (int r = 0; r < 4; ++r) {
                    float vv = sv[qq][kt][r] * SC;
                    const int kg = kbase + kt * 16 + hi * 4 + r;
                    if (edge) vv = (kg <= qg) ? vv : -INFINITY;
                    pv[r] = __builtin_amdgcn_exp2f(vv);
                    lsum[qq] += pv[r];
                }
                *(uint2*)&Pw[swz(qq * 16 + q15, kt * 32 + hi * 8)] =
                    make_uint2(cvt2(pv[0], pv[1]), cvt2(pv[2], pv[3]));
            }
        }

        // PV: O^T += V^T * P^T  (V frags shared by both Q-streams)
        #pragma unroll
        for (int ks2 = 0; ks2 < 2; ++ks2) {
            bf16x8 vf[4];
            #pragma unroll
            for (int dt = 0; dt < 4; ++dt)
                vf[dt] = *(const bf16x8*)&Vs[p][swz(dt * 16 + q15, ks2 * 64 + hi * 16)];
            #pragma unroll
            for (int qq = 0; qq < 2; ++qq) {
                bf16x8 pf = *(const bf16x8*)&Pw[swz(qq * 16 + q15, ks2 * 64 + hi * 16)];
                #pragma unroll
                for (int dt = 0; dt < 4; ++dt)
                    accO[qq][dt] = __builtin_amdgcn_mfma_f32_16x16x32_bf16(vf[dt], pf, accO[qq][dt], 0, 0, 0);
            }
        }

        __syncthreads();                          // next buffer staged + bufs free
        p ^= 1;
    }

    // l reduce over hi groups
    #pragma unroll
    for (int qq = 0; qq < 2; ++qq) {
        lsum[qq] += __shfl_xor(lsum[qq], 16);
        lsum[qq] += __shfl_xor(lsum[qq], 32);
    }

    // partial write: O^T [64d][128q], wave w owns q-cols w*32..+32
    float* partO = Pws + ((size_t)b * 144 + pb128(qi) + sl) * PART128_F;
    #pragma unroll
    for (int qq = 0; qq < 2; ++qq) {
        #pragma unroll
        for (int dt = 0; dt < 4; ++dt)
            #pragma unroll
            for (int r = 0; r < 4; ++r)
                partO[(dt * 16 + hi * 4 + r) * 128 + w * 32 + qq * 16 + q15] = accO[qq][dt][r];
        if (hi == 0) partO[8192 + w * 32 + qq * 16 + q15] = lsum[qq];
    }
}

// ---------------------------------------------------------------------------
// Pass 2: sum <=8 slice partials per (b, 128-row q-tile), transpose via LDS,
// normalize by l, write O.
// ---------------------------------------------------------------------------
__global__ __launch_bounds__(256) void attn_merge_kernel(
    const float* __restrict__ Pws, float* __restrict__ O)
{
    __shared__ float Tr[64 * 132];                // [d][q] pad 132
    __shared__ float Ls[128];

    const int tid = threadIdx.x;
    const int b   = blockIdx.x & 3;
    const int qi  = blockIdx.x >> 2;
    const int np  = (qi >> 2) + 1;                // slices(qi) <= 8
    const float* base = Pws + ((size_t)b * 144 + pb128(qi)) * PART128_F;

    {
        const int d  = tid >> 2;
        const int qg = (tid & 3) * 32;
        float s[32];
        #pragma unroll
        for (int i = 0; i < 32; ++i) s[i] = 0.f;
        for (int pp = 0; pp < np; ++pp) {
            const float* sp = base + (size_t)pp * PART128_F + d * 128 + qg;
            #pragma unroll
            for (int i = 0; i < 8; ++i) {
                float4 v = *(const float4*)(sp + i * 4);
                s[4*i]   += v.x; s[4*i+1] += v.y;
                s[4*i+2] += v.z; s[4*i+3] += v.w;
            }
        }
        #pragma unroll
        for (int i = 0; i < 32; ++i) Tr[d * 132 + qg + i] = s[i];
    }
    if (tid < 128) {
        float L = 0.f;
        for (int pp = 0; pp < np; ++pp) L += base[(size_t)pp * PART128_F + 8192 + tid];
        Ls[tid] = 1.0f / L;
    }
    __syncthreads();
    {
        const int q  = tid >> 1;
        const int dg = (tid & 1) * 32;
        const float rL = Ls[q];
        float* dst = O + ((size_t)b * N_ + qi * 128 + q) * D_ + dg;
        #pragma unroll
        for (int i = 0; i < 8; ++i) {
            float4 v = make_float4(Tr[(dg + 4*i    ) * 132 + q] * rL,
                                   Tr[(dg + 4*i + 1) * 132 + q] * rL,
                                   Tr[(dg + 4*i + 2) * 132 + q] * rL,
                                   Tr[(dg + 4*i + 3) * 132 + q] * rL);
            *(float4*)(dst + i * 4) = v;
        }
    }
}

// ---------------------------------------------------------------------------
extern "C" void kernel_launch(void* const* d_in, const int* in_sizes, int n_in,
                              void* d_out, int out_size, void* d_ws, size_t ws_size,
                              hipStream_t stream)
{
    const float* x  = (const float*)d_in[0];
    const float* Wk = (const float*)d_in[1];
    const float* Wq = (const float*)d_in[2];
    const float* Wv = (const float*)d_in[3];
    float* O = (float*)d_out;

    const size_t per = (size_t)4 * N_ * D_;       // 1M bf16 elements each
    unsigned short* Kb = (unsigned short*)d_ws;
    unsigned short* Qb = Kb + per;
    unsigned short* Vt = Qb + per;
    float* Pws = (float*)((char*)d_ws + 3 * per * sizeof(unsigned short));

    proj_kernel<<<dim3(4 * N_ / 64), 512, 0, stream>>>(x, Wk, Wq, Wv, Kb, Qb, Vt);
    attn_part_kernel<<<dim3(576), 256, 0, stream>>>(Qb, Kb, Vt, Pws);
    attn_merge_kernel<<<dim3(128), 256, 0, stream>>>(Pws, O);
}

// Round 12
// 55.305 us; speedup vs baseline: 1.1356x; 1.0294x over previous
//
#include <hip/hip_runtime.h>
#include <hip/hip_bf16.h>
#include <math.h>

#define N_   4096
#define DIN  512
#define D_   64

typedef __attribute__((ext_vector_type(8))) short  bf16x8;
typedef __attribute__((ext_vector_type(4))) float  f32x4;

#define ZERO4 ((f32x4){0.f, 0.f, 0.f, 0.f})

__device__ __forceinline__ unsigned short bf16rne(float x) {
    unsigned u = __float_as_uint(x);
    return (unsigned short)((u + 0x7FFFu + ((u >> 16) & 1u)) >> 16);
}
__device__ __forceinline__ unsigned cvt2(float a, float b) {
    __hip_bfloat162 h = __float22bfloat162_rn(make_float2(a, b));
    unsigned u; __builtin_memcpy(&u, &h, 4);
    return u;
}
__device__ __forceinline__ uint2 cvt4(float4 v) {
    return make_uint2(cvt2(v.x, v.y), cvt2(v.z, v.w));
}
// VALU cross-lane half-swaps (gfx950)
__device__ __forceinline__ void pl32swap(unsigned &a, unsigned &b) {
    asm volatile("v_permlane32_swap_b32 %0, %1" : "+v"(a), "+v"(b));
}
__device__ __forceinline__ void pl16swap(unsigned &a, unsigned &b) {
    asm volatile("v_permlane16_swap_b32 %0, %1" : "+v"(a), "+v"(b));
}
// XOR-swizzled short-index for [row][128B] tiles: byte_in_row ^ ((row&7)<<4)
__device__ __forceinline__ int swz(int row, int byte_in_row) {
    return (row * 128 + (byte_in_row ^ ((row & 7) << 4))) >> 1;
}

// async 16B global->LDS (linear LDS dest = wave base + lane*16)
#define GLD16(gp, lp)                                                          \
    __builtin_amdgcn_global_load_lds(                                          \
        (const __attribute__((address_space(1))) unsigned int*)(gp),           \
        (__attribute__((address_space(3))) unsigned int*)(lp), 16, 0, 0)

// slices per 128-row q-tile: s(qi) = (qi>>2)+1 (8-chunk slices, nch = 2qi+2)
// prefix pb128(qi) = qi + 2g(g-1) + r*g, g=qi>>2, r=qi&3; 144 slots per batch
__device__ __forceinline__ int pb128(int qi) {
    const int g = qi >> 2, r = qi & 3;
    return qi + 2 * g * (g - 1) + r * g;
}
#define PART128_F 8320   // 128*64 O + 128 l (floats)

// ---------------------------------------------------------------------------
// Projection GEMM (unchanged): X fp32 -> {K,Q n-major bf16, Vt o-major bf16}.
// ---------------------------------------------------------------------------
__global__ __launch_bounds__(512) void proj_kernel(
    const float* __restrict__ X, const float* __restrict__ Wk,
    const float* __restrict__ Wq, const float* __restrict__ Wv,
    unsigned short* __restrict__ Kb, unsigned short* __restrict__ Qb,
    unsigned short* __restrict__ Vt)
{
    __shared__ unsigned short Xs[2][64 * 64];
    __shared__ unsigned short Ws[2][192 * 64];

    const int tid  = threadIdx.x;
    const int lane = tid & 63;
    const int w    = tid >> 6;
    const int q15  = lane & 15;
    const int hi   = lane >> 4;
    const int rt   = w >> 1;
    const int oh   = w & 1;
    const int rbase = blockIdx.x * 64;

    float4 xr[2], wr[6];

    auto loadT = [&](int kc) {
        #pragma unroll
        for (int i = 0; i < 2; ++i) {
            const int idx = tid + i * 512;
            xr[i] = *(const float4*)(X + (size_t)(rbase + (idx >> 4)) * DIN + kc + (idx & 15) * 4);
        }
        #pragma unroll
        for (int i = 0; i < 6; ++i) {
            const int idx  = tid + i * 512;
            const int wrow = idx >> 4;
            const float* Wp = (wrow < 64)  ? Wk + (size_t)wrow * DIN
                            : (wrow < 128) ? Wq + (size_t)(wrow - 64) * DIN
                                           : Wv + (size_t)(wrow - 128) * DIN;
            wr[i] = *(const float4*)(Wp + kc + (idx & 15) * 4);
        }
    };
    auto storeT = [&](int p) {
        #pragma unroll
        for (int i = 0; i < 2; ++i) {
            const int idx = tid + i * 512;
            *(uint2*)&Xs[p][swz(idx >> 4, (idx & 15) * 8)] = cvt4(xr[i]);
        }
        #pragma unroll
        for (int i = 0; i < 6; ++i) {
            const int idx = tid + i * 512;
            *(uint2*)&Ws[p][swz(idx >> 4, (idx & 15) * 8)] = cvt4(wr[i]);
        }
    };

    f32x4 acc[6];
    #pragma unroll
    for (int i = 0; i < 6; ++i) acc[i] = ZERO4;

    loadT(0);
    int p = 0;
    for (int it = 0; it < 8; ++it) {
        storeT(p);
        __syncthreads();
        if (it < 7) loadT((it + 1) * 64);
        #pragma unroll
        for (int ks = 0; ks < 2; ++ks) {
            bf16x8 af = *(const bf16x8*)&Xs[p][swz(rt * 16 + q15, ks * 64 + hi * 16)];
            #pragma unroll
            for (int j = 0; j < 6; ++j) {
                bf16x8 bfr = *(const bf16x8*)&Ws[p][swz((oh * 6 + j) * 16 + q15, ks * 64 + hi * 16)];
                acc[j] = __builtin_amdgcn_mfma_f32_16x16x32_bf16(af, bfr, acc[j], 0, 0, 0);
            }
        }
        p ^= 1;
    }

    unsigned short* Os = &Ws[0][0];               // [64n][66o] V staging scratch
    #pragma unroll
    for (int j = 0; j < 6; ++j) {
        const int og = oh * 6 + j;
        #pragma unroll
        for (int r = 0; r < 4; ++r) {
            const int n = rt * 16 + hi * 4 + r;
            const int o = og * 16 + q15;
            unsigned short v = bf16rne(acc[j][r]);
            if (og < 4)      Kb[(size_t)(rbase + n) * D_ + o]        = v;
            else if (og < 8) Qb[(size_t)(rbase + n) * D_ + (o - 64)] = v;
            else             Os[n * 66 + (o - 128)]                  = v;
        }
    }
    __syncthreads();
    {
        const int o  = tid >> 3;
        const int ng = (tid & 7) * 8;
        unsigned short tmp[8];
        #pragma unroll
        for (int i = 0; i < 8; ++i) tmp[i] = Os[(ng + i) * 66 + o];
        const int b  = rbase >> 12;
        const int nb = rbase & (N_ - 1);
        *(uint4*)(Vt + ((size_t)b * D_ + o) * N_ + nb + ng) = *(uint4*)&tmp[0];
    }
}

// ---------------------------------------------------------------------------
// Pass 1: partial attention, in-register P (permlane swaps, no P LDS).
// Block = 4 waves x 128 q-rows (2 Q-streams/wave), k-slice <=8 chunks, 576
// blocks. K/V via global_load_lds (linear dest, inverse-swizzled source),
// double-buffered, ONE barrier/chunk. PV computes O[q][d] = P*V directly.
// No-max softmax -> additive partials [128q][64d]+l[128].
// ---------------------------------------------------------------------------
__global__ __launch_bounds__(256) void attn_part_kernel(
    const unsigned short* __restrict__ Qb, const unsigned short* __restrict__ Kb,
    const unsigned short* __restrict__ Vt, float* __restrict__ Pws)
{
    __shared__ unsigned short Ks[2][64 * 64];     // [key][d] swizzled
    __shared__ unsigned short Vs[2][64 * 64];     // [d][key] swizzled

    const int tid  = threadIdx.x;
    const int lane = tid & 63;
    const int w    = tid >> 6;
    const int q15  = lane & 15;
    const int hi   = lane >> 4;

    const int b = blockIdx.x & 3;                 // XCD-pinned batch
    const int u = blockIdx.x >> 2;                // 0..143
    const int v = 143 - u;                        // big q-tiles first
    int g = 0;
    #pragma unroll
    for (int t = 0; t < 7; ++t)
        if (2 * (t + 1) * (t + 2) <= v) g = t + 1;
    const int idx = v - 2 * g * (g + 1);
    const int qs  = idx / (g + 1);
    const int qi  = 4 * g + qs;                   // 0..31
    const int sl  = idx - qs * (g + 1);           // 0..g

    const int nch  = 2 * qi + 2;
    const int cbeg = sl * 8;
    const int cend = min(nch, cbeg + 8);
    const int qb   = qi * 128;

    const unsigned short* Qp = Qb + (size_t)b * N_ * D_;
    const unsigned short* Kp = Kb + (size_t)b * N_ * D_;
    const unsigned short* Vp = Vt + (size_t)b * D_ * N_;

    bf16x8 qf[2][2];
    #pragma unroll
    for (int qq = 0; qq < 2; ++qq)
        #pragma unroll
        for (int ks = 0; ks < 2; ++ks)
            qf[qq][ks] = *(const bf16x8*)(Qp + (size_t)(qb + w * 32 + qq * 16 + q15) * D_ + ks * 32 + hi * 8);

    f32x4 accO[2][4];
    #pragma unroll
    for (int qq = 0; qq < 2; ++qq)
        #pragma unroll
        for (int dt = 0; dt < 4; ++dt) accO[qq][dt] = ZERO4;
    float lsum[2] = {0.f, 0.f};

    // inverse-swizzled per-lane source offset (shorts): 16B slot (l&7)^(l>>3)
    const int lsw = 8 * ((lane & 7) ^ (lane >> 3));

    auto issueChunk = [&](int p, int c) {
        const int kb2 = c * 64;
        #pragma unroll
        for (int i = 0; i < 2; ++i) {
            const int r8  = w * 2 + i;            // 8-row group 0..7
            const int row = r8 * 8 + (lane >> 3);
            GLD16(Kp + (size_t)(kb2 + row) * D_ + lsw, &Ks[p][r8 * 512]);
            GLD16(Vp + (size_t)row * N_ + kb2 + lsw,   &Vs[p][r8 * 512]);
        }
    };

    issueChunk(0, cbeg);
    __syncthreads();                              // drains vmcnt + barrier

    const float SC = 0.125f * 1.44269504f;        // log2-domain scale
    int p = 0;

    for (int c = cbeg; c < cend; ++c) {
        if (c + 1 < cend) issueChunk(p ^ 1, c + 1);   // overlap with compute
        const int kbase = c * 64;
        const bool edge = (c >= nch - 2);         // diagonal chunks

        // QK^T (swapped): S^T[k][q], K frags shared by both Q-streams
        f32x4 sv[2][4];
        #pragma unroll
        for (int kt = 0; kt < 4; ++kt) {
            bf16x8 k0 = *(const bf16x8*)&Ks[p][swz(kt * 16 + q15, hi * 16)];
            bf16x8 k1 = *(const bf16x8*)&Ks[p][swz(kt * 16 + q15, 64 + hi * 16)];
            sv[0][kt] = __builtin_amdgcn_mfma_f32_16x16x32_bf16(k0, qf[0][0], ZERO4, 0, 0, 0);
            sv[0][kt] = __builtin_amdgcn_mfma_f32_16x16x32_bf16(k1, qf[0][1], sv[0][kt], 0, 0, 0);
            sv[1][kt] = __builtin_amdgcn_mfma_f32_16x16x32_bf16(k0, qf[1][0], ZERO4, 0, 0, 0);
            sv[1][kt] = __builtin_amdgcn_mfma_f32_16x16x32_bf16(k1, qf[1][1], sv[1][kt], 0, 0, 0);
        }

        #pragma unroll
        for (int qq = 0; qq < 2; ++qq) {
            const int qg = qb + w * 32 + qq * 16 + q15;
            // softmax-lite -> packed pairs pk[kt][rp] (pair m = kt*8+hi*2+rp)
            unsigned pk[4][2];
            #pragma unroll
            for (int kt = 0; kt < 4; ++kt) {
                float pv[4];
                #pragma unroll
                for (int r = 0; r < 4; ++r) {
                    float vv = sv[qq][kt][r] * SC;
                    const int kg = kbase + kt * 16 + hi * 4 + r;
                    if (edge) vv = (kg <= qg) ? vv : -INFINITY;
                    pv[r] = __builtin_amdgcn_exp2f(vv);
                    lsum[qq] += pv[r];
                }
                pk[kt][0] = cvt2(pv[0], pv[1]);
                pk[kt][1] = cvt2(pv[2], pv[3]);
            }
            // redistribute to A-frag P[q=q15][k=ks2*32+hi*8+j] via permlane
            #pragma unroll
            for (int ks2 = 0; ks2 < 2; ++ks2) {
                unsigned a0 = pk[2 * ks2][0],     a1 = pk[2 * ks2][1];
                unsigned b0 = pk[2 * ks2 + 1][0], b1 = pk[2 * ks2 + 1][1];
                pl32swap(a0, b0);
                pl32swap(a1, b1);
                pl16swap(a0, b0);
                pl16swap(a1, b1);
                unsigned pw[4] = {a0, a1, b0, b1};
                bf16x8 pa;
                __builtin_memcpy(&pa, pw, 16);
                // PV: O[q][d] += P * V   (V frags shared across qq via LDS)
                #pragma unroll
                for (int dt = 0; dt < 4; ++dt) {
                    bf16x8 vf = *(const bf16x8*)&Vs[p][swz(dt * 16 + q15, ks2 * 64 + hi * 16)];
                    accO[qq][dt] = __builtin_amdgcn_mfma_f32_16x16x32_bf16(pa, vf, accO[qq][dt], 0, 0, 0);
                }
            }
        }

        __syncthreads();                          // next buffer staged + bufs free
        p ^= 1;
    }

    // l reduce over hi groups
    #pragma unroll
    for (int qq = 0; qq < 2; ++qq) {
        lsum[qq] += __shfl_xor(lsum[qq], 16);
        lsum[qq] += __shfl_xor(lsum[qq], 32);
    }

    // partial write: O [128q][64d]; lane(q15,hi) holds q = ..+hi*4+r, d = dt*16+q15
    float* partO = Pws + ((size_t)b * 144 + pb128(qi) + sl) * PART128_F;
    #pragma unroll
    for (int qq = 0; qq < 2; ++qq) {
        #pragma unroll
        for (int dt = 0; dt < 4; ++dt)
            #pragma unroll
            for (int r = 0; r < 4; ++r)
                partO[(w * 32 + qq * 16 + hi * 4 + r) * 64 + dt * 16 + q15] = accO[qq][dt][r];
        if (hi == 0) partO[8192 + w * 32 + qq * 16 + q15] = lsum[qq];
    }
}

// ---------------------------------------------------------------------------
// Pass 2: sum <=8 slice partials ([128q][64d] layout -> no transpose),
// normalize by l, write O.
// ---------------------------------------------------------------------------
__global__ __launch_bounds__(256) void attn_merge_kernel(
    const float* __restrict__ Pws, float* __restrict__ O)
{
    const int tid = threadIdx.x;
    const int b   = blockIdx.x & 3;
    const int qi  = blockIdx.x >> 2;
    const int np  = (qi >> 2) + 1;                // slices(qi) <= 8
    const float* base = Pws + ((size_t)b * 144 + pb128(qi)) * PART128_F;

    const int q  = tid >> 1;                      // 0..127
    const int dg = (tid & 1) * 32;                // 0 or 32

    float s[32];
    #pragma unroll
    for (int i = 0; i < 32; ++i) s[i] = 0.f;
    float L = 0.f;
    for (int pp = 0; pp < np; ++pp) {
        const float* sp = base + (size_t)pp * PART128_F + q * 64 + dg;
        #pragma unroll
        for (int i = 0; i < 8; ++i) {
            float4 v = *(const float4*)(sp + i * 4);
            s[4*i]   += v.x; s[4*i+1] += v.y;
            s[4*i+2] += v.z; s[4*i+3] += v.w;
        }
        L += base[(size_t)pp * PART128_F + 8192 + q];
    }
    const float rL = 1.0f / L;
    float* dst = O + ((size_t)b * N_ + qi * 128 + q) * D_ + dg;
    #pragma unroll
    for (int i = 0; i < 8; ++i)
        *(float4*)(dst + i * 4) = make_float4(s[4*i] * rL, s[4*i+1] * rL,
                                              s[4*i+2] * rL, s[4*i+3] * rL);
}

// ---------------------------------------------------------------------------
extern "C" void kernel_launch(void* const* d_in, const int* in_sizes, int n_in,
                              void* d_out, int out_size, void* d_ws, size_t ws_size,
                              hipStream_t stream)
{
    const float* x  = (const float*)d_in[0];
    const float* Wk = (const float*)d_in[1];
    const float* Wq = (const float*)d_in[2];
    const float* Wv = (const float*)d_in[3];
    float* O = (float*)d_out;

    const size_t per = (size_t)4 * N_ * D_;       // 1M bf16 elements each
    unsigned short* Kb = (unsigned short*)d_ws;
    unsigned short* Qb = Kb + per;
    unsigned short* Vt = Qb + per;
    float* Pws = (float*)((char*)d_ws + 3 * per * sizeof(unsigned short));

    proj_kernel<<<dim3(4 * N_ / 64), 512, 0, stream>>>(x, Wk, Wq, Wv, Kb, Qb, Vt);
    attn_part_kernel<<<dim3(576), 256, 0, stream>>>(Qb, Kb, Vt, Pws);
    attn_merge_kernel<<<dim3(128), 256, 0, stream>>>(Pws, O);
}